// Round 1
// baseline (157.321 us; speedup 1.0000x reference)
//
#include <hip/hip_runtime.h>
#include <stdint.h>

#define NTETS   200000
#define FEATS   128
#define OUTF    128
#define NG      5
#define BM      128
#define NBLOCKS ((NTETS + BM - 1) / BM)

typedef __attribute__((ext_vector_type(8))) short  short8v;
typedef __attribute__((ext_vector_type(4))) float  f32x4;

static __device__ __forceinline__ unsigned short bf16_rne(float f) {
  union { float f; unsigned u; } v; v.f = f;
  unsigned r = v.u + 0x7FFFu + ((v.u >> 16) & 1u);
  return (unsigned short)(r >> 16);
}

static __device__ __forceinline__ void gload_lds16(const void* g, void* l) {
  __builtin_amdgcn_global_load_lds(
      (const __attribute__((address_space(1))) unsigned int*)g,
      (__attribute__((address_space(3))) unsigned int*)l, 16, 0, 0);
}

// Detect whether neighbor indices are stored as int64 (odd int32 words all 0)
// or int32. Deterministic for fixed input data.
__global__ void detect_mode_k(const int* __restrict__ nbr, int* __restrict__ flag) {
  int t = threadIdx.x;
  int nz = 0;
  for (int i = t; i < 4096; i += 64) nz |= nbr[2 * i + 1];
  unsigned long long any = __ballot(nz != 0);
  if (t == 0) flag[0] = (any == 0ULL) ? 1 : 0;   // 1 => int64 indices
}

// Pre-convert W (fp32 [128][640]) into 5 chunk images, each the exact
// XOR-swizzled bf16 LDS layout [n=128][k=128], so main-kernel staging is a
// linear global_load_lds copy.
__global__ void prep_w_k(const float* __restrict__ W, unsigned short* __restrict__ wimg) {
  int id = blockIdx.x * 256 + threadIdx.x;
  if (id >= NG * 128 * 128) return;
  int g = id >> 14, rem = id & 16383;
  int n = rem >> 7, k = rem & 127;
  float w = W[n * (NG * FEATS) + g * FEATS + k];
  int byteoff = (g << 15) + (n << 8) + ((k << 1) ^ ((n & 7) << 4));
  wimg[byteoff >> 1] = bf16_rne(w);
}

__global__ __launch_bounds__(256) void conv_mfma_k(
    const float* __restrict__ feat, const int* __restrict__ nbr,
    const float* __restrict__ bias, const unsigned short* __restrict__ wimg,
    const int* __restrict__ mode, float* __restrict__ out)
{
  __shared__ __align__(16) char lds[65536];   // [0,32K): A tile, [32K,64K): W tile
  const int t    = threadIdx.x;
  const int row0 = blockIdx.x * BM;
  const int lane = t & 63;
  const int wv   = t >> 6;
  const int wm   = wv >> 1, wn = wv & 1;      // 2x2 wave grid, 64x64 tiles
  const int lr   = lane & 15;
  const int lk   = lane >> 4;

  // staging role: 2 threads per row, 64 fp32 (256B) each
  const int sr = t >> 1, sh = t & 1;
  const int gr = row0 + sr;
  const bool valid = gr < NTETS;
  const bool m64 = (*mode != 0);

  int srcs[NG];
  srcs[0] = valid ? gr : 0;
  {
    long b4 = (long)gr * 4;
#pragma unroll
    for (int q = 0; q < 4; ++q) {
      int s = valid ? (m64 ? nbr[2 * (b4 + q)] : nbr[b4 + q]) : 0;
      srcs[q + 1] = ((unsigned)s < (unsigned)NTETS) ? s : 0;
    }
  }

  const f32x4 zero = {0.f, 0.f, 0.f, 0.f};
  f32x4 acc[4][4];
#pragma unroll
  for (int i = 0; i < 4; ++i) {
#pragma unroll
    for (int j = 0; j < 4; ++j) acc[i][j] = zero;
  }

  const int aswz = (sr & 7) << 4;   // staging-write swizzle
  const int rswz = (lr & 7) << 4;   // fragment-read swizzle (row&7 == lr&7)

  for (int g = 0; g < NG; ++g) {
    if (g) __syncthreads();
    // ---- stage W chunk: 32 KiB linear copy of pre-swizzled image ----
    {
      const char* src = (const char*)wimg + (g << 15) + t * 16;
      char* dst = lds + 32768 + t * 16;
#pragma unroll
      for (int i = 0; i < 8; ++i)
        gload_lds16(src + (i << 12), dst + (i << 12));
    }
    // ---- stage A chunk: gathered fp32 rows -> bf16, swizzled ds_write_b128 ----
    {
      const f32x4* s = (const f32x4*)(feat + (long)srcs[g] * FEATS + sh * 64);
      char* arow = lds + sr * 256;
#pragma unroll
      for (int j = 0; j < 8; ++j) {
        f32x4 f0 = s[2 * j];
        f32x4 f1 = s[2 * j + 1];
        short8v v;
        v[0] = (short)bf16_rne(f0[0]); v[1] = (short)bf16_rne(f0[1]);
        v[2] = (short)bf16_rne(f0[2]); v[3] = (short)bf16_rne(f0[3]);
        v[4] = (short)bf16_rne(f1[0]); v[5] = (short)bf16_rne(f1[1]);
        v[6] = (short)bf16_rne(f1[2]); v[7] = (short)bf16_rne(f1[3]);
        *(short8v*)(arow + (((sh << 7) + (j << 4)) ^ aswz)) = v;
      }
    }
    __syncthreads();
    // ---- compute: K=128 chunk = 4 steps of K=32 ----
#pragma unroll
    for (int kk = 0; kk < 4; ++kk) {
      short8v a[4], b[4];
#pragma unroll
      for (int ms = 0; ms < 4; ++ms) {
        int off = (wm * 64 + ms * 16 + lr) * 256 + (((kk << 6) + (lk << 4)) ^ rswz);
        a[ms] = *(const short8v*)(lds + off);
      }
#pragma unroll
      for (int ns = 0; ns < 4; ++ns) {
        int off = 32768 + (wn * 64 + ns * 16 + lr) * 256 + (((kk << 6) + (lk << 4)) ^ rswz);
        b[ns] = *(const short8v*)(lds + off);
      }
#pragma unroll
      for (int ms = 0; ms < 4; ++ms) {
#pragma unroll
        for (int ns = 0; ns < 4; ++ns)
          acc[ms][ns] = __builtin_amdgcn_mfma_f32_16x16x32_bf16(a[ms], b[ns], acc[ms][ns], 0, 0, 0);
      }
    }
  }

  // ---- epilogue: bias + relu + fp32 store (C layout: col=l&15, row=(l>>4)*4+reg) ----
#pragma unroll
  for (int ns = 0; ns < 4; ++ns) {
    const int col = wn * 64 + ns * 16 + lr;
    const float bv = bias[col];
#pragma unroll
    for (int ms = 0; ms < 4; ++ms) {
      const int rbase = row0 + wm * 64 + ms * 16 + lk * 4;
#pragma unroll
      for (int i = 0; i < 4; ++i) {
        int r = rbase + i;
        if (r < NTETS) {
          float vv = acc[ms][ns][i] + bv;
          out[(long)r * OUTF + col] = vv > 0.f ? vv : 0.f;
        }
      }
    }
  }
}

extern "C" void kernel_launch(void* const* d_in, const int* in_sizes, int n_in,
                              void* d_out, int out_size, void* d_ws, size_t ws_size,
                              hipStream_t stream) {
  const float* feat = (const float*)d_in[0];
  const int*   nbr  = (const int*)d_in[1];
  const float* W    = (const float*)d_in[2];
  const float* bias = (const float*)d_in[3];
  float* out = (float*)d_out;

  int* mode = (int*)d_ws;
  unsigned short* wimg = (unsigned short*)((char*)d_ws + 1024);

  detect_mode_k<<<1, 64, 0, stream>>>(nbr, mode);
  prep_w_k<<<320, 256, 0, stream>>>(W, wimg);
  conv_mfma_k<<<NBLOCKS, 256, 0, stream>>>(feat, nbr, bias, wimg, mode, out);
}